// Round 2
// baseline (212.473 us; speedup 1.0000x reference)
//
#include <hip/hip_runtime.h>
#include <math.h>

#define BB   8
#define HH   384
#define WW   384
#define NN   96
#define HWSZ (HH * WW)
#define NSEG (NN - 1)
#define SEGF 12
#define DMAXV 15.0f

// ---------------------------------------------------------------------------
// Kernel 1: 7x7 cross-correlation (SAME, zero pad) of pred and |pred| with the
// 2-channel Gaussian-edge filter, scaled by EXTGRADFAC=10.
// Output layout: interleaved channels g2[b][y][x][c] (c=0: y-force, c=1: x-force)
// so one bilinear corner = one 8B load in the snake kernel.
// Interior fast path (97% of pixels) skips per-tap bounds predication.
// ---------------------------------------------------------------------------
__global__ __launch_bounds__(256) void conv_kernel(
    const float* __restrict__ pred, const float* __restrict__ fltr,
    float* __restrict__ g2, float* __restrict__ gw2)
{
    __shared__ float sf[98];  // [2][49]
    int tid = threadIdx.x;
    if (tid < 98) sf[tid] = fltr[tid];
    __syncthreads();

    int gidx = blockIdx.x * 256 + tid;     // 0 .. B*HW-1 (exact grid)
    int b = gidx / HWSZ;
    int p = gidx - b * HWSZ;
    int y = p / WW;
    int x = p - y * WW;
    const float* pb = pred + b * HWSZ;

    float a0 = 0.f, a1 = 0.f, a2 = 0.f, a3 = 0.f;
    if (y >= 3 && y < HH - 3 && x >= 3 && x < WW - 3) {
        const float* base = pb + (y - 3) * WW + (x - 3);
#pragma unroll
        for (int ky = 0; ky < 7; ++ky) {
#pragma unroll
            for (int kx = 0; kx < 7; ++kx) {
                float v  = base[ky * WW + kx];
                float f0 = sf[ky * 7 + kx];
                float f1 = sf[49 + ky * 7 + kx];
                float av = fabsf(v);
                a0 = fmaf(v,  f0, a0);
                a1 = fmaf(v,  f1, a1);
                a2 = fmaf(av, f0, a2);
                a3 = fmaf(av, f1, a3);
            }
        }
    } else {
#pragma unroll
        for (int ky = 0; ky < 7; ++ky) {
            int iy = y + ky - 3;
            bool oky = (iy >= 0) && (iy < HH);
            const float* row = pb + iy * WW;
#pragma unroll
            for (int kx = 0; kx < 7; ++kx) {
                int ix = x + kx - 3;
                float v = (oky && ix >= 0 && ix < WW) ? row[ix] : 0.0f;
                float f0 = sf[ky * 7 + kx];
                float f1 = sf[49 + ky * 7 + kx];
                float av = fabsf(v);
                a0 = fmaf(v,  f0, a0);
                a1 = fmaf(v,  f1, a1);
                a2 = fmaf(av, f0, a2);
                a3 = fmaf(av, f1, a3);
            }
        }
    }
    float2* gb  = (float2*)g2  + (size_t)b * HWSZ;
    float2* gwb = (float2*)gw2 + (size_t)b * HWSZ;
    gb[p]  = make_float2(a0 * 10.0f, a1 * 10.0f);
    gwb[p] = make_float2(a2 * 10.0f, a3 * 10.0f);
}

// bilinear sample of a channel-interleaved 2-ch image; ref-identical math
__device__ inline float2 bilin2i(const float2* __restrict__ img, float py, float px)
{
    float y = fminf(fmaxf(py, 0.0f), (float)(HH - 1));
    float x = fminf(fmaxf(px, 0.0f), (float)(WW - 1));
    int y0 = (int)floorf(y);
    int x0 = (int)floorf(x);
    int y1 = min(y0 + 1, HH - 1);
    int x1 = min(x0 + 1, WW - 1);
    float wy = y - (float)y0;
    float wx = x - (float)x0;
    float2 v00 = img[y0 * WW + x0];
    float2 v01 = img[y0 * WW + x1];
    float2 v10 = img[y1 * WW + x0];
    float2 v11 = img[y1 * WW + x1];
    float w00 = (1.f - wy) * (1.f - wx);
    float w01 = (1.f - wy) * wx;
    float w10 = wy * (1.f - wx);
    float w11 = wy * wx;
    return make_float2(v00.x * w00 + v01.x * w01 + v10.x * w10 + v11.x * w11,
                       v00.y * w00 + v01.y * w01 + v10.y * w10 + v11.y * w11);
}

__device__ inline void write_seg(float* __restrict__ r,
                                 float py, float px, float qy, float qx, float wseg)
{
    float aby = qy - py, abx = qx - px;
    float denom = aby * aby + abx * abx + 1e-8f;
    float aab = py * aby + px * abx;
    float aa  = py * py + px * px;
    float reach = DMAXV + wseg;
    r[0]  = py;   r[1]  = px;
    r[2]  = aby;  r[3]  = abx;
    r[4]  = aab;  r[5]  = denom;
    r[6]  = 1.0f / denom;
    r[7]  = aa;   r[8]  = wseg;
    r[9]  = fminf(py, qy) - reach;
    r[10] = fmaxf(py, qy) + reach;
    r[11] = 0.f;
}

// ---------------------------------------------------------------------------
// Kernel 2: snake evolution — ONE WAVE per sample, thread t owns nodes 2t,2t+1.
// All neighbor exchange via shuffles: zero barriers, zero LDS in the hot loop.
// Lanes 48..63 run on dummy zeros (harmless, clamped loads) to avoid exec churn.
// Also zeroes the cross-kernel reduction slots (accum, counter) for render.
// ---------------------------------------------------------------------------
__global__ __launch_bounds__(64) void snake_kernel(
    const float* __restrict__ nodes, const float* __restrict__ widths,
    const float* __restrict__ g2, const float* __restrict__ gw2,
    float* __restrict__ segs, float* __restrict__ accum,
    unsigned int* __restrict__ counter)
{
    int b = blockIdx.x;
    int t = threadIdx.x;           // 0..63, active t<48
    if (b == 0 && t == 0) { *accum = 0.f; *counter = 0u; }

    const float2* gb  = (const float2*)g2  + (size_t)b * HWSZ;
    const float2* gwb = (const float2*)gw2 + (size_t)b * HWSZ;
    const int HALF = NN / 2;       // 48
    bool act = (t < HALF);

    float ay = 0.f, ax = 0.f, by = 0.f, bx = 0.f;
    if (act) {
        const float* np = nodes + (size_t)(b * NN + 2 * t) * 2;
        ay = np[0]; ax = np[1]; by = np[2]; bx = np[3];
    }

    // ---- 50 position steps ----
    for (int s = 0; s < 50; ++s) {
        // issue the gathers FIRST so load latency overlaps the shuffle chain
        float2 fa = bilin2i(gb, ay, ax);
        float2 fb = bilin2i(gb, by, bx);

        float bLy = __shfl_up(by, 1, 64), bLx = __shfl_up(bx, 1, 64);
        float aRy = __shfl_down(ay, 1, 64), aRx = __shfl_down(ax, 1, 64);
        bLy = (t == 0) ? ay : bLy;  bLx = (t == 0) ? ax : bLx;          // x[-1]=x[0]
        aRy = (t == HALF - 1) ? by : aRy;  aRx = (t == HALF - 1) ? bx : aRx;  // x[96]=x[95]

        float d2ay = bLy - 2.f * ay + by,  d2ax = bLx - 2.f * ax + bx;
        float d2by = ay  - 2.f * by + aRy, d2bx = ax  - 2.f * bx + aRx;

        float d2bLy = __shfl_up(d2by, 1, 64), d2bLx = __shfl_up(d2bx, 1, 64);
        float d2aRy = __shfl_down(d2ay, 1, 64), d2aRx = __shfl_down(d2ax, 1, 64);
        d2bLy = (t == 0) ? d2ay : d2bLy;  d2bLx = (t == 0) ? d2ax : d2bLx;
        d2aRy = (t == HALF - 1) ? d2by : d2aRy;  d2aRx = (t == HALF - 1) ? d2bx : d2aRx;

        float d4ay = d2bLy - 2.f * d2ay + d2by,  d4ax = d2bLx - 2.f * d2ax + d2bx;
        float d4by = d2ay  - 2.f * d2by + d2aRy, d4bx = d2ax  - 2.f * d2bx + d2aRx;

        ay += 0.1f * (0.01f * d2ay - 0.01f * d4ay + fa.x);
        ax += 0.1f * (0.01f * d2ax - 0.01f * d4ax + fa.y);
        by += 0.1f * (0.01f * d2by - 0.01f * d4by + fb.x);
        bx += 0.1f * (0.01f * d2bx - 0.01f * d4bx + fb.y);
    }

    // ---- tangent / outward normal ----
    {
        float bLy = __shfl_up(by, 1, 64), bLx = __shfl_up(bx, 1, 64);
        float aRy = __shfl_down(ay, 1, 64), aRx = __shfl_down(ax, 1, 64);
        float tay = 0.5f * (by - bLy), tax = 0.5f * (bx - bLx);
        if (t == 0) { tay = by - ay; tax = bx - ax; }           // t[0]=x[1]-x[0]
        float tby = 0.5f * (aRy - ay), tbx = 0.5f * (aRx - ax);
        if (t == HALF - 1) { tby = by - ay; tbx = bx - ax; }    // t[95]=x[95]-x[94]

        float na0 = -tax, na1 = tay;
        float nrm = sqrtf(na0 * na0 + na1 * na1) + 1e-6f;
        float nay = na0 / nrm, nax = na1 / nrm;
        float nb0 = -tbx, nb1 = tby;
        nrm = sqrtf(nb0 * nb0 + nb1 * nb1) + 1e-6f;
        float nby = nb0 / nrm, nbx = nb1 / nrm;

        // ---- 10 width steps ----
        float wa = 0.f, wb = 0.f;
        if (act) { wa = widths[b * NN + 2 * t]; wb = widths[b * NN + 2 * t + 1]; }
        for (int s = 0; s < 10; ++s) {
            float2 pa = bilin2i(gwb, ay + wa * nay, ax + wa * nax);
            float2 ma = bilin2i(gwb, ay - wa * nay, ax - wa * nax);
            float2 pb = bilin2i(gwb, by + wb * nby, bx + wb * nbx);
            float2 mb = bilin2i(gwb, by - wb * nby, bx - wb * nbx);
            float fa = 0.5f * ((pa.x * nay + pa.y * nax) - (ma.x * nay + ma.y * nax));
            float fb = 0.5f * ((pb.x * nby + pb.y * nbx) - (mb.x * nby + mb.y * nbx));
            wa = fmaxf(wa + 0.1f * fa, 0.5f);
            wb = fmaxf(wb + 0.1f * fb, 0.5f);
        }

        // ---- segment records ----
        float aRy2 = __shfl_down(ay, 1, 64), aRx2 = __shfl_down(ax, 1, 64);
        float waR  = __shfl_down(wa, 1, 64);
        if (act) {
            float* r0 = segs + (size_t)(b * NSEG + 2 * t) * SEGF;
            write_seg(r0, ay, ax, by, bx, 0.5f * (wa + wb));        // seg 2t: node 2t -> 2t+1
            if (t < HALF - 1) {
                float* r1 = segs + (size_t)(b * NSEG + 2 * t + 1) * SEGF;
                write_seg(r1, by, bx, aRy2, aRx2, 0.5f * (wb + waR)); // seg 2t+1
            }
        }
    }
}

// ---------------------------------------------------------------------------
// Kernel 3: render distance map row-by-row + MSE, fused grid reduction.
// One block per (b, row); uniform [lo,hi] segment window prunes 95 -> ~12.
// Last block (device-scope atomic counter) writes the mean to d_out.
// ---------------------------------------------------------------------------
__global__ __launch_bounds__(384) void render_kernel(
    const float* __restrict__ pred, const float* __restrict__ segs,
    float* __restrict__ accum, unsigned int* __restrict__ counter,
    float* __restrict__ out)
{
    __shared__ float ss[NSEG * SEGF];
    __shared__ int slo, shi;
    __shared__ float swsum[6];

    int b = blockIdx.x / HH;
    int y = blockIdx.x - b * HH;
    int t = threadIdx.x;          // pixel x (0..383)

    const float* sb = segs + (size_t)b * NSEG * SEGF;
    for (int j = t; j < NSEG * SEGF; j += 384) ss[j] = sb[j];
    if (t == 0) { slo = NSEG; shi = -1; }
    __syncthreads();

    float py = (float)y;
    if (t < NSEG) {
        float ylo = ss[t * SEGF + 9];
        float yhi = ss[t * SEGF + 10];
        if (py >= ylo && py <= yhi) {
            atomicMin(&slo, t);
            atomicMax(&shi, t);
        }
    }
    __syncthreads();

    float px = (float)t;
    float pp = py * py + px * px;
    float minv = DMAXV;

    int lo = slo, hi = shi;
    for (int si = lo; si <= hi; ++si) {
        const float* r = ss + si * SEGF;
        float dotpa = fmaf(py, r[2], fmaf(px, r[3], -r[4]));
        float tt = fminf(fmaxf(dotpa * r[6], 0.0f), 1.0f);
        float pa2 = fmaf(py, -2.0f * r[0], fmaf(px, -2.0f * r[1], pp + r[7]));
        float d2 = fmaf(tt, fmaf(tt, r[5], -2.0f * dotpa), pa2);
        float d = sqrtf(fmaxf(d2, 0.0f));
        float v = fmaxf(d - r[8], 0.0f);
        minv = fminf(minv, v);
    }

    float pr = pred[(size_t)b * HWSZ + y * WW + t];
    float diff = pr - minv;
    float sq = diff * diff;

#pragma unroll
    for (int off = 32; off > 0; off >>= 1) sq += __shfl_down(sq, off, 64);
    if ((t & 63) == 0) swsum[t >> 6] = sq;
    __syncthreads();
    if (t == 0) {
        float tot = swsum[0] + swsum[1] + swsum[2] + swsum[3] + swsum[4] + swsum[5];
        atomicAdd(accum, tot);
        __threadfence();
        unsigned int done = atomicAdd(counter, 1u);
        if (done == (unsigned int)(BB * HH - 1)) {
            float total = atomicAdd(accum, 0.0f);   // coherent re-read
            out[0] = total * (1.0f / (float)(BB * HWSZ));
        }
    }
}

extern "C" void kernel_launch(void* const* d_in, const int* in_sizes, int n_in,
                              void* d_out, int out_size, void* d_ws, size_t ws_size,
                              hipStream_t stream)
{
    const float* pred   = (const float*)d_in[0];   // (8,1,384,384)
    const float* nodes  = (const float*)d_in[1];   // (8,96,2)
    const float* widths = (const float*)d_in[2];   // (8,96)
    const float* fltr   = (const float*)d_in[3];   // (2,1,7,7)
    float* out = (float*)d_out;

    float* ws   = (float*)d_ws;
    float* g2   = ws;                               // B*HW*2 (interleaved)
    float* gw2  = g2 + (size_t)BB * 2 * HWSZ;       // B*HW*2
    float* segs = gw2 + (size_t)BB * 2 * HWSZ;      // B*95*12
    float* accum = segs + (size_t)BB * NSEG * SEGF; // 1
    unsigned int* counter = (unsigned int*)(accum + 1);

    conv_kernel<<<(BB * HWSZ) / 256, 256, 0, stream>>>(pred, fltr, g2, gw2);
    snake_kernel<<<BB, 64, 0, stream>>>(nodes, widths, g2, gw2, segs, accum, counter);
    render_kernel<<<BB * HH, 384, 0, stream>>>(pred, segs, accum, counter, out);
}

// Round 3
// 163.903 us; speedup vs baseline: 1.2963x; 1.2963x over previous
//
#include <hip/hip_runtime.h>
#include <math.h>

#define BB   8
#define HH   384
#define WW   384
#define NN   96
#define HWSZ (HH * WW)
#define NSEG (NN - 1)
#define SEGF 12
#define DMAXV 15.0f
#define ROWS_PER_BLK 12
#define NCHUNK (HH / ROWS_PER_BLK)   // 32

// ---------------------------------------------------------------------------
// Kernel 1: 7x7 cross-correlation (SAME, zero pad) of pred and |pred| with the
// 2-channel Gaussian-edge filter, scaled by EXTGRADFAC=10.
// Output layout: interleaved channels g2[b][y][x][c] so one bilinear corner is
// one 8B load in the snake kernel. Interior fast path skips bounds predication.
// ---------------------------------------------------------------------------
__global__ __launch_bounds__(256) void conv_kernel(
    const float* __restrict__ pred, const float* __restrict__ fltr,
    float* __restrict__ g2, float* __restrict__ gw2)
{
    __shared__ float sf[98];  // [2][49]
    int tid = threadIdx.x;
    if (tid < 98) sf[tid] = fltr[tid];
    __syncthreads();

    int gidx = blockIdx.x * 256 + tid;     // 0 .. B*HW-1 (exact grid)
    int b = gidx / HWSZ;
    int p = gidx - b * HWSZ;
    int y = p / WW;
    int x = p - y * WW;
    const float* pb = pred + b * HWSZ;

    float a0 = 0.f, a1 = 0.f, a2 = 0.f, a3 = 0.f;
    if (y >= 3 && y < HH - 3 && x >= 3 && x < WW - 3) {
        const float* base = pb + (y - 3) * WW + (x - 3);
#pragma unroll
        for (int ky = 0; ky < 7; ++ky) {
#pragma unroll
            for (int kx = 0; kx < 7; ++kx) {
                float v  = base[ky * WW + kx];
                float f0 = sf[ky * 7 + kx];
                float f1 = sf[49 + ky * 7 + kx];
                float av = fabsf(v);
                a0 = fmaf(v,  f0, a0);
                a1 = fmaf(v,  f1, a1);
                a2 = fmaf(av, f0, a2);
                a3 = fmaf(av, f1, a3);
            }
        }
    } else {
#pragma unroll
        for (int ky = 0; ky < 7; ++ky) {
            int iy = y + ky - 3;
            bool oky = (iy >= 0) && (iy < HH);
            const float* row = pb + iy * WW;
#pragma unroll
            for (int kx = 0; kx < 7; ++kx) {
                int ix = x + kx - 3;
                float v = (oky && ix >= 0 && ix < WW) ? row[ix] : 0.0f;
                float f0 = sf[ky * 7 + kx];
                float f1 = sf[49 + ky * 7 + kx];
                float av = fabsf(v);
                a0 = fmaf(v,  f0, a0);
                a1 = fmaf(v,  f1, a1);
                a2 = fmaf(av, f0, a2);
                a3 = fmaf(av, f1, a3);
            }
        }
    }
    float2* gb  = (float2*)g2  + (size_t)b * HWSZ;
    float2* gwb = (float2*)gw2 + (size_t)b * HWSZ;
    gb[p]  = make_float2(a0 * 10.0f, a1 * 10.0f);
    gwb[p] = make_float2(a2 * 10.0f, a3 * 10.0f);
}

// bilinear sample of a channel-interleaved 2-ch image; ref-identical math
__device__ inline float2 bilin2i(const float2* __restrict__ img, float py, float px)
{
    float y = fminf(fmaxf(py, 0.0f), (float)(HH - 1));
    float x = fminf(fmaxf(px, 0.0f), (float)(WW - 1));
    int y0 = (int)floorf(y);
    int x0 = (int)floorf(x);
    int y1 = min(y0 + 1, HH - 1);
    int x1 = min(x0 + 1, WW - 1);
    float wy = y - (float)y0;
    float wx = x - (float)x0;
    float2 v00 = img[y0 * WW + x0];
    float2 v01 = img[y0 * WW + x1];
    float2 v10 = img[y1 * WW + x0];
    float2 v11 = img[y1 * WW + x1];
    float w00 = (1.f - wy) * (1.f - wx);
    float w01 = (1.f - wy) * wx;
    float w10 = wy * (1.f - wx);
    float w11 = wy * wx;
    return make_float2(v00.x * w00 + v01.x * w01 + v10.x * w10 + v11.x * w11,
                       v00.y * w00 + v01.y * w01 + v10.y * w10 + v11.y * w11);
}

__device__ inline void write_seg(float* __restrict__ r,
                                 float py, float px, float qy, float qx, float wseg)
{
    float aby = qy - py, abx = qx - px;
    float denom = aby * aby + abx * abx + 1e-8f;
    float aab = py * aby + px * abx;
    float aa  = py * py + px * px;
    float reach = DMAXV + wseg;
    r[0]  = py;   r[1]  = px;
    r[2]  = aby;  r[3]  = abx;
    r[4]  = aab;  r[5]  = denom;
    r[6]  = 1.0f / denom;
    r[7]  = aa;   r[8]  = wseg;
    r[9]  = fminf(py, qy) - reach;
    r[10] = fmaxf(py, qy) + reach;
    r[11] = 0.f;
}

// ---------------------------------------------------------------------------
// Kernel 2: snake evolution — ONE WAVE per sample, thread t owns nodes 2t,2t+1.
// All neighbor exchange via shuffles: zero barriers, zero LDS in the hot loop.
// ---------------------------------------------------------------------------
__global__ __launch_bounds__(64) void snake_kernel(
    const float* __restrict__ nodes, const float* __restrict__ widths,
    const float* __restrict__ g2, const float* __restrict__ gw2,
    float* __restrict__ segs)
{
    int b = blockIdx.x;
    int t = threadIdx.x;           // 0..63, active t<48

    const float2* gb  = (const float2*)g2  + (size_t)b * HWSZ;
    const float2* gwb = (const float2*)gw2 + (size_t)b * HWSZ;
    const int HALF = NN / 2;       // 48
    bool act = (t < HALF);

    float ay = 0.f, ax = 0.f, by = 0.f, bx = 0.f;
    if (act) {
        const float* np = nodes + (size_t)(b * NN + 2 * t) * 2;
        ay = np[0]; ax = np[1]; by = np[2]; bx = np[3];
    }

    // ---- 50 position steps ----
    for (int s = 0; s < 50; ++s) {
        // issue the gathers FIRST so load latency overlaps the shuffle chain
        float2 fa = bilin2i(gb, ay, ax);
        float2 fb = bilin2i(gb, by, bx);

        float bLy = __shfl_up(by, 1, 64), bLx = __shfl_up(bx, 1, 64);
        float aRy = __shfl_down(ay, 1, 64), aRx = __shfl_down(ax, 1, 64);
        bLy = (t == 0) ? ay : bLy;  bLx = (t == 0) ? ax : bLx;          // x[-1]=x[0]
        aRy = (t == HALF - 1) ? by : aRy;  aRx = (t == HALF - 1) ? bx : aRx;  // x[96]=x[95]

        float d2ay = bLy - 2.f * ay + by,  d2ax = bLx - 2.f * ax + bx;
        float d2by = ay  - 2.f * by + aRy, d2bx = ax  - 2.f * bx + aRx;

        float d2bLy = __shfl_up(d2by, 1, 64), d2bLx = __shfl_up(d2bx, 1, 64);
        float d2aRy = __shfl_down(d2ay, 1, 64), d2aRx = __shfl_down(d2ax, 1, 64);
        d2bLy = (t == 0) ? d2ay : d2bLy;  d2bLx = (t == 0) ? d2ax : d2bLx;
        d2aRy = (t == HALF - 1) ? d2by : d2aRy;  d2aRx = (t == HALF - 1) ? d2bx : d2aRx;

        float d4ay = d2bLy - 2.f * d2ay + d2by,  d4ax = d2bLx - 2.f * d2ax + d2bx;
        float d4by = d2ay  - 2.f * d2by + d2aRy, d4bx = d2ax  - 2.f * d2bx + d2aRx;

        ay += 0.1f * (0.01f * d2ay - 0.01f * d4ay + fa.x);
        ax += 0.1f * (0.01f * d2ax - 0.01f * d4ax + fa.y);
        by += 0.1f * (0.01f * d2by - 0.01f * d4by + fb.x);
        bx += 0.1f * (0.01f * d2bx - 0.01f * d4bx + fb.y);
    }

    // ---- tangent / outward normal ----
    {
        float bLy = __shfl_up(by, 1, 64), bLx = __shfl_up(bx, 1, 64);
        float aRy = __shfl_down(ay, 1, 64), aRx = __shfl_down(ax, 1, 64);
        float tay = 0.5f * (by - bLy), tax = 0.5f * (bx - bLx);
        if (t == 0) { tay = by - ay; tax = bx - ax; }           // t[0]=x[1]-x[0]
        float tby = 0.5f * (aRy - ay), tbx = 0.5f * (aRx - ax);
        if (t == HALF - 1) { tby = by - ay; tbx = bx - ax; }    // t[95]=x[95]-x[94]

        float na0 = -tax, na1 = tay;
        float nrm = sqrtf(na0 * na0 + na1 * na1) + 1e-6f;
        float nay = na0 / nrm, nax = na1 / nrm;
        float nb0 = -tbx, nb1 = tby;
        nrm = sqrtf(nb0 * nb0 + nb1 * nb1) + 1e-6f;
        float nby = nb0 / nrm, nbx = nb1 / nrm;

        // ---- 10 width steps ----
        float wa = 0.f, wb = 0.f;
        if (act) { wa = widths[b * NN + 2 * t]; wb = widths[b * NN + 2 * t + 1]; }
        for (int s = 0; s < 10; ++s) {
            float2 pa = bilin2i(gwb, ay + wa * nay, ax + wa * nax);
            float2 ma = bilin2i(gwb, ay - wa * nay, ax - wa * nax);
            float2 pb = bilin2i(gwb, by + wb * nby, bx + wb * nbx);
            float2 mb = bilin2i(gwb, by - wb * nby, bx - wb * nbx);
            float fa = 0.5f * ((pa.x * nay + pa.y * nax) - (ma.x * nay + ma.y * nax));
            float fb = 0.5f * ((pb.x * nby + pb.y * nbx) - (mb.x * nby + mb.y * nbx));
            wa = fmaxf(wa + 0.1f * fa, 0.5f);
            wb = fmaxf(wb + 0.1f * fb, 0.5f);
        }

        // ---- segment records ----
        float aRy2 = __shfl_down(ay, 1, 64), aRx2 = __shfl_down(ax, 1, 64);
        float waR  = __shfl_down(wa, 1, 64);
        if (act) {
            float* r0 = segs + (size_t)(b * NSEG + 2 * t) * SEGF;
            write_seg(r0, ay, ax, by, bx, 0.5f * (wa + wb));        // seg 2t
            if (t < HALF - 1) {
                float* r1 = segs + (size_t)(b * NSEG + 2 * t + 1) * SEGF;
                write_seg(r1, by, bx, aRy2, aRx2, 0.5f * (wb + waR)); // seg 2t+1
            }
        }
    }
}

// ---------------------------------------------------------------------------
// Kernel 3: render 12 rows per block (8 images x 32 chunks = 256 blocks).
// Segs staged once, ONE uniform window per chunk (exact: seg reach bounds
// already include DMAX+ws). Loop interchange: outer segs (params loaded from
// LDS once into registers), inner 12 rows with register minv[] accumulators.
// Per-block MSE partial -> partials[]; no same-address atomic storm.
// ---------------------------------------------------------------------------
__global__ __launch_bounds__(384) void render_kernel(
    const float* __restrict__ pred, const float* __restrict__ segs,
    float* __restrict__ partials)
{
    __shared__ float ss[NSEG * SEGF];
    __shared__ int slo, shi;
    __shared__ float swsum[6];

    int blk = blockIdx.x;
    int b = blk / NCHUNK;
    int chunk = blk - b * NCHUNK;
    int y0 = chunk * ROWS_PER_BLK;
    int t = threadIdx.x;          // pixel x (0..383)

    const float* sb = segs + (size_t)b * NSEG * SEGF;
    for (int j = t; j < NSEG * SEGF; j += 384) ss[j] = sb[j];
    if (t == 0) { slo = NSEG; shi = -1; }
    __syncthreads();

    float cy0 = (float)y0, cy1 = (float)(y0 + ROWS_PER_BLK - 1);
    if (t < NSEG) {
        float ylo = ss[t * SEGF + 9];
        float yhi = ss[t * SEGF + 10];
        if (yhi >= cy0 && ylo <= cy1) {
            atomicMin(&slo, t);
            atomicMax(&shi, t);
        }
    }
    __syncthreads();
    int lo = slo, hi = shi;

    float px = (float)t;
    float px2 = px * px;
    float minv[ROWS_PER_BLK];
#pragma unroll
    for (int r = 0; r < ROWS_PER_BLK; ++r) minv[r] = DMAXV;

    for (int si = lo; si <= hi; ++si) {
        const float* r = ss + si * SEGF;
        float ay = r[0], ax = r[1], aby = r[2], abx = r[3];
        float aab = r[4], denom = r[5], invd = r[6], aa = r[7], ws = r[8];
        float dotpa_b = fmaf(px, abx, -aab);
        float pa2_b   = fmaf(px, -2.0f * ax, px2 + aa);
#pragma unroll
        for (int ry = 0; ry < ROWS_PER_BLK; ++ry) {
            float py = (float)(y0 + ry);
            float dotpa = fmaf(py, aby, dotpa_b);
            float tt = fminf(fmaxf(dotpa * invd, 0.0f), 1.0f);
            float pa2 = fmaf(py, fmaf(py, 1.0f, -2.0f * ay), pa2_b);
            float d2 = fmaf(tt, fmaf(tt, denom, -2.0f * dotpa), pa2);
            float d = sqrtf(fmaxf(d2, 0.0f));
            float v = fmaxf(d - ws, 0.0f);
            minv[ry] = fminf(minv[ry], v);
        }
    }

    const float* pb = pred + (size_t)b * HWSZ + (size_t)y0 * WW + t;
    float sq = 0.f;
#pragma unroll
    for (int ry = 0; ry < ROWS_PER_BLK; ++ry) {
        float diff = pb[ry * WW] - minv[ry];
        sq = fmaf(diff, diff, sq);
    }

#pragma unroll
    for (int off = 32; off > 0; off >>= 1) sq += __shfl_down(sq, off, 64);
    if ((t & 63) == 0) swsum[t >> 6] = sq;
    __syncthreads();
    if (t == 0) {
        partials[blk] = swsum[0] + swsum[1] + swsum[2] + swsum[3] + swsum[4] + swsum[5];
    }
}

// ---------------------------------------------------------------------------
// Kernel 4: reduce 256 partials -> mean -> d_out[0]
// ---------------------------------------------------------------------------
__global__ __launch_bounds__(256) void finalize_kernel(
    const float* __restrict__ partials, float* __restrict__ out)
{
    __shared__ float sred[4];
    int t = threadIdx.x;
    float s = partials[t];
#pragma unroll
    for (int off = 32; off > 0; off >>= 1) s += __shfl_down(s, off, 64);
    if ((t & 63) == 0) sred[t >> 6] = s;
    __syncthreads();
    if (t == 0) {
        out[0] = (sred[0] + sred[1] + sred[2] + sred[3]) * (1.0f / (float)(BB * HWSZ));
    }
}

extern "C" void kernel_launch(void* const* d_in, const int* in_sizes, int n_in,
                              void* d_out, int out_size, void* d_ws, size_t ws_size,
                              hipStream_t stream)
{
    const float* pred   = (const float*)d_in[0];   // (8,1,384,384)
    const float* nodes  = (const float*)d_in[1];   // (8,96,2)
    const float* widths = (const float*)d_in[2];   // (8,96)
    const float* fltr   = (const float*)d_in[3];   // (2,1,7,7)
    float* out = (float*)d_out;

    float* ws   = (float*)d_ws;
    float* g2   = ws;                               // B*HW*2 (interleaved)
    float* gw2  = g2 + (size_t)BB * 2 * HWSZ;       // B*HW*2
    float* segs = gw2 + (size_t)BB * 2 * HWSZ;      // B*95*12
    float* partials = segs + (size_t)BB * NSEG * SEGF; // 256

    conv_kernel<<<(BB * HWSZ) / 256, 256, 0, stream>>>(pred, fltr, g2, gw2);
    snake_kernel<<<BB, 64, 0, stream>>>(nodes, widths, g2, gw2, segs);
    render_kernel<<<BB * NCHUNK, 384, 0, stream>>>(pred, segs, partials);
    finalize_kernel<<<1, 256, 0, stream>>>(partials, out);
}

// Round 4
// 153.458 us; speedup vs baseline: 1.3846x; 1.0681x over previous
//
#include <hip/hip_runtime.h>
#include <math.h>

#define BB   8
#define HH   384
#define WW   384
#define NN   96
#define HWSZ (HH * WW)
#define NSEG (NN - 1)
#define SEGF 12
#define DMAXV 15.0f
#define ROWS_PER_BLK 12
#define NCHUNK (HH / ROWS_PER_BLK)   // 32

// ---------------------------------------------------------------------------
// Separable 7x7: fy = outer(dg,g), fx = outer(g,dg). Recover 1-D taps from the
// input filter exactly: g[j] = sum_i |fy[i][j]| (since sum|dg|=1),
// dg[i] = sum_j fy[i][j] (since sum g = 1).
// ---------------------------------------------------------------------------
__device__ inline void load_taps(const float* __restrict__ fltr,
                                 float* __restrict__ sg, float* __restrict__ sdg)
{
    int tid = threadIdx.x;
    if (tid < 7) {
        float s = 0.f;
#pragma unroll
        for (int i = 0; i < 7; ++i) s += fabsf(fltr[i * 7 + tid]);
        sg[tid] = s;
    } else if (tid < 14) {
        int r = tid - 7;
        float s = 0.f;
#pragma unroll
        for (int j = 0; j < 7; ++j) s += fltr[r * 7 + j];
        sdg[r] = s;
    }
    __syncthreads();
}

// ---------------------------------------------------------------------------
// Kernel 1a: horizontal pass. Per pixel: 7 row-neighbor loads ->
// hbuf = (g*p, dg*p, g*|p|, dg*|p|) as float4.
// ---------------------------------------------------------------------------
__global__ __launch_bounds__(256) void conv_h(
    const float* __restrict__ pred, const float* __restrict__ fltr,
    float4* __restrict__ hbuf)
{
    __shared__ float sg[7], sdg[7];
    load_taps(fltr, sg, sdg);

    int gidx = blockIdx.x * 256 + threadIdx.x;   // exact grid: B*HW
    int b = gidx / HWSZ;
    int p = gidx - b * HWSZ;
    int y = p / WW;
    int x = p - y * WW;
    const float* row = pred + (size_t)b * HWSZ + y * WW;

    float hg = 0.f, hd = 0.f, hga = 0.f, hda = 0.f;
    if (x >= 3 && x < WW - 3) {
#pragma unroll
        for (int k = 0; k < 7; ++k) {
            float v  = row[x + k - 3];
            float av = fabsf(v);
            hg  = fmaf(v,  sg[k],  hg);
            hd  = fmaf(v,  sdg[k], hd);
            hga = fmaf(av, sg[k],  hga);
            hda = fmaf(av, sdg[k], hda);
        }
    } else {
#pragma unroll
        for (int k = 0; k < 7; ++k) {
            int ix = x + k - 3;
            float v  = (ix >= 0 && ix < WW) ? row[ix] : 0.f;
            float av = fabsf(v);
            hg  = fmaf(v,  sg[k],  hg);
            hd  = fmaf(v,  sdg[k], hd);
            hga = fmaf(av, sg[k],  hga);
            hda = fmaf(av, sdg[k], hda);
        }
    }
    hbuf[gidx] = make_float4(hg, hd, hga, hda);
}

// ---------------------------------------------------------------------------
// Kernel 1b: vertical pass. Per pixel: 7 coalesced float4 column loads ->
// g2 = (dg.hg, g.hd)*10, gw2 = (dg.hga, g.hda)*10, channel-interleaved.
// ---------------------------------------------------------------------------
__global__ __launch_bounds__(256) void conv_v(
    const float4* __restrict__ hbuf, const float* __restrict__ fltr,
    float2* __restrict__ g2, float2* __restrict__ gw2)
{
    __shared__ float sg[7], sdg[7];
    load_taps(fltr, sg, sdg);

    int gidx = blockIdx.x * 256 + threadIdx.x;
    int b = gidx / HWSZ;
    int p = gidx - b * HWSZ;
    int y = p / WW;
    int x = p - y * WW;
    const float4* col = hbuf + (size_t)b * HWSZ + x;

    float o0 = 0.f, o1 = 0.f, o2 = 0.f, o3 = 0.f;
    if (y >= 3 && y < HH - 3) {
#pragma unroll
        for (int k = 0; k < 7; ++k) {
            float4 h = col[(y + k - 3) * WW];
            o0 = fmaf(h.x, sdg[k], o0);
            o1 = fmaf(h.y, sg[k],  o1);
            o2 = fmaf(h.z, sdg[k], o2);
            o3 = fmaf(h.w, sg[k],  o3);
        }
    } else {
#pragma unroll
        for (int k = 0; k < 7; ++k) {
            int iy = y + k - 3;
            if (iy >= 0 && iy < HH) {
                float4 h = col[iy * WW];
                o0 = fmaf(h.x, sdg[k], o0);
                o1 = fmaf(h.y, sg[k],  o1);
                o2 = fmaf(h.z, sdg[k], o2);
                o3 = fmaf(h.w, sg[k],  o3);
            }
        }
    }
    g2[gidx]  = make_float2(o0 * 10.f, o1 * 10.f);
    gw2[gidx] = make_float2(o2 * 10.f, o3 * 10.f);
}

// bilinear sample of a channel-interleaved 2-ch image; ref-identical math
__device__ inline float2 bilin2i(const float2* __restrict__ img, float py, float px)
{
    float y = fminf(fmaxf(py, 0.0f), (float)(HH - 1));
    float x = fminf(fmaxf(px, 0.0f), (float)(WW - 1));
    int y0 = (int)floorf(y);
    int x0 = (int)floorf(x);
    int y1 = min(y0 + 1, HH - 1);
    int x1 = min(x0 + 1, WW - 1);
    float wy = y - (float)y0;
    float wx = x - (float)x0;
    float2 v00 = img[y0 * WW + x0];
    float2 v01 = img[y0 * WW + x1];
    float2 v10 = img[y1 * WW + x0];
    float2 v11 = img[y1 * WW + x1];
    float w00 = (1.f - wy) * (1.f - wx);
    float w01 = (1.f - wy) * wx;
    float w10 = wy * (1.f - wx);
    float w11 = wy * wx;
    return make_float2(v00.x * w00 + v01.x * w01 + v10.x * w10 + v11.x * w11,
                       v00.y * w00 + v01.y * w01 + v10.y * w10 + v11.y * w11);
}

__device__ inline void write_seg(float* __restrict__ r,
                                 float py, float px, float qy, float qx, float wseg)
{
    float aby = qy - py, abx = qx - px;
    float denom = aby * aby + abx * abx + 1e-8f;
    float aab = py * aby + px * abx;
    float aa  = py * py + px * px;
    float reach = DMAXV + wseg;
    r[0]  = py;   r[1]  = px;
    r[2]  = aby;  r[3]  = abx;
    r[4]  = aab;  r[5]  = denom;
    r[6]  = 1.0f / denom;
    r[7]  = aa;   r[8]  = wseg;
    r[9]  = fminf(py, qy) - reach;
    r[10] = fmaxf(py, qy) + reach;
    r[11] = 0.f;
}

// ---------------------------------------------------------------------------
// Kernel 2: snake evolution — ONE WAVE per sample, thread t owns nodes 2t,2t+1.
// d4 computed DIRECTLY from the 5-point stencil: one (non-dependent) shuffle
// level per step; the whole shuffle chain hides under the bilinear gather.
// ---------------------------------------------------------------------------
__global__ __launch_bounds__(64) void snake_kernel(
    const float* __restrict__ nodes, const float* __restrict__ widths,
    const float* __restrict__ g2, const float* __restrict__ gw2,
    float* __restrict__ segs)
{
    int b = blockIdx.x;
    int t = threadIdx.x;           // 0..63, active t<48

    const float2* gb  = (const float2*)g2  + (size_t)b * HWSZ;
    const float2* gwb = (const float2*)gw2 + (size_t)b * HWSZ;
    const int HALF = NN / 2;       // 48
    bool act = (t < HALF);
    bool t0 = (t == 0), tl = (t == HALF - 1);

    float ay = 0.f, ax = 0.f, by = 0.f, bx = 0.f;
    if (act) {
        float4 n4 = *(const float4*)(nodes + (size_t)(b * NN + 2 * t) * 2);
        ay = n4.x; ax = n4.y; by = n4.z; bx = n4.w;
    }

    // ---- 50 position steps ----
    for (int s = 0; s < 50; ++s) {
        // gathers first: load latency overlaps the shuffle/stencil chain
        float2 fa = bilin2i(gb, ay, ax);
        float2 fb = bilin2i(gb, by, bx);

        float aLy = __shfl_up(ay, 1, 64),  aLx = __shfl_up(ax, 1, 64);   // x[2t-2]
        float bLy = __shfl_up(by, 1, 64),  bLx = __shfl_up(bx, 1, 64);   // x[2t-1]
        float aRy = __shfl_down(ay, 1, 64), aRx = __shfl_down(ax, 1, 64); // x[2t+2]
        float bRy = __shfl_down(by, 1, 64), bRx = __shfl_down(bx, 1, 64); // x[2t+3]
        bLy = t0 ? ay : bLy;  bLx = t0 ? ax : bLx;     // x[-1] := x[0]
        aRy = tl ? by : aRy;  aRx = tl ? bx : aRx;     // x[96] := x[95]

        // d2 at 2t-1, 2t, 2t+1, 2t+2 (open BC), then d4 = d2_open(d2)
        float d2m_y = aLy - 2.f * bLy + ay;
        float d2a_y = bLy - 2.f * ay + by;
        float d2b_y = ay  - 2.f * by + aRy;
        float d2p_y = by  - 2.f * aRy + bRy;
        d2m_y = t0 ? d2a_y : d2m_y;                    // d2[-1] := d2[0]
        d2p_y = tl ? d2b_y : d2p_y;                    // d2[96] := d2[95]
        float d4a_y = d2m_y - 2.f * d2a_y + d2b_y;
        float d4b_y = d2a_y - 2.f * d2b_y + d2p_y;

        float d2m_x = aLx - 2.f * bLx + ax;
        float d2a_x = bLx - 2.f * ax + bx;
        float d2b_x = ax  - 2.f * bx + aRx;
        float d2p_x = bx  - 2.f * aRx + bRx;
        d2m_x = t0 ? d2a_x : d2m_x;
        d2p_x = tl ? d2b_x : d2p_x;
        float d4a_x = d2m_x - 2.f * d2a_x + d2b_x;
        float d4b_x = d2a_x - 2.f * d2b_x + d2p_x;

        ay += 0.1f * (0.01f * d2a_y - 0.01f * d4a_y + fa.x);
        ax += 0.1f * (0.01f * d2a_x - 0.01f * d4a_x + fa.y);
        by += 0.1f * (0.01f * d2b_y - 0.01f * d4b_y + fb.x);
        bx += 0.1f * (0.01f * d2b_x - 0.01f * d4b_x + fb.y);
    }

    // ---- tangent / outward normal ----
    {
        float bLy = __shfl_up(by, 1, 64), bLx = __shfl_up(bx, 1, 64);
        float aRy = __shfl_down(ay, 1, 64), aRx = __shfl_down(ax, 1, 64);
        float tay = 0.5f * (by - bLy), tax = 0.5f * (bx - bLx);
        if (t0) { tay = by - ay; tax = bx - ax; }
        float tby = 0.5f * (aRy - ay), tbx = 0.5f * (aRx - ax);
        if (tl) { tby = by - ay; tbx = bx - ax; }

        float na0 = -tax, na1 = tay;
        float nrm = sqrtf(na0 * na0 + na1 * na1) + 1e-6f;
        float nay = na0 / nrm, nax = na1 / nrm;
        float nb0 = -tbx, nb1 = tby;
        nrm = sqrtf(nb0 * nb0 + nb1 * nb1) + 1e-6f;
        float nby = nb0 / nrm, nbx = nb1 / nrm;

        // ---- 10 width steps ----
        float wa = 0.f, wb = 0.f;
        if (act) { wa = widths[b * NN + 2 * t]; wb = widths[b * NN + 2 * t + 1]; }
        for (int s = 0; s < 10; ++s) {
            float2 pa = bilin2i(gwb, ay + wa * nay, ax + wa * nax);
            float2 ma = bilin2i(gwb, ay - wa * nay, ax - wa * nax);
            float2 pb = bilin2i(gwb, by + wb * nby, bx + wb * nbx);
            float2 mb = bilin2i(gwb, by - wb * nby, bx - wb * nbx);
            float fa = 0.5f * ((pa.x * nay + pa.y * nax) - (ma.x * nay + ma.y * nax));
            float fb = 0.5f * ((pb.x * nby + pb.y * nbx) - (mb.x * nby + mb.y * nbx));
            wa = fmaxf(wa + 0.1f * fa, 0.5f);
            wb = fmaxf(wb + 0.1f * fb, 0.5f);
        }

        // ---- segment records ----
        float aRy2 = __shfl_down(ay, 1, 64), aRx2 = __shfl_down(ax, 1, 64);
        float waR  = __shfl_down(wa, 1, 64);
        if (act) {
            float* r0 = segs + (size_t)(b * NSEG + 2 * t) * SEGF;
            write_seg(r0, ay, ax, by, bx, 0.5f * (wa + wb));
            if (t < HALF - 1) {
                float* r1 = segs + (size_t)(b * NSEG + 2 * t + 1) * SEGF;
                write_seg(r1, by, bx, aRy2, aRx2, 0.5f * (wb + waR));
            }
        }
    }
}

// ---------------------------------------------------------------------------
// Kernel 3: render 12 rows per block (256 blocks). Uniform per-chunk segment
// window; outer-seg / inner-row loop with register minv[] accumulators.
// ---------------------------------------------------------------------------
__global__ __launch_bounds__(384) void render_kernel(
    const float* __restrict__ pred, const float* __restrict__ segs,
    float* __restrict__ partials)
{
    __shared__ float ss[NSEG * SEGF];
    __shared__ int slo, shi;
    __shared__ float swsum[6];

    int blk = blockIdx.x;
    int b = blk / NCHUNK;
    int chunk = blk - b * NCHUNK;
    int y0 = chunk * ROWS_PER_BLK;
    int t = threadIdx.x;

    const float* sb = segs + (size_t)b * NSEG * SEGF;
    for (int j = t; j < NSEG * SEGF; j += 384) ss[j] = sb[j];
    if (t == 0) { slo = NSEG; shi = -1; }
    __syncthreads();

    float cy0 = (float)y0, cy1 = (float)(y0 + ROWS_PER_BLK - 1);
    if (t < NSEG) {
        float ylo = ss[t * SEGF + 9];
        float yhi = ss[t * SEGF + 10];
        if (yhi >= cy0 && ylo <= cy1) {
            atomicMin(&slo, t);
            atomicMax(&shi, t);
        }
    }
    __syncthreads();
    int lo = slo, hi = shi;

    float px = (float)t;
    float px2 = px * px;
    float minv[ROWS_PER_BLK];
#pragma unroll
    for (int r = 0; r < ROWS_PER_BLK; ++r) minv[r] = DMAXV;

    for (int si = lo; si <= hi; ++si) {
        const float* r = ss + si * SEGF;
        float ay = r[0], ax = r[1], aby = r[2], abx = r[3];
        float aab = r[4], denom = r[5], invd = r[6], aa = r[7], ws = r[8];
        float dotpa_b = fmaf(px, abx, -aab);
        float pa2_b   = fmaf(px, -2.0f * ax, px2 + aa);
#pragma unroll
        for (int ry = 0; ry < ROWS_PER_BLK; ++ry) {
            float py = (float)(y0 + ry);
            float dotpa = fmaf(py, aby, dotpa_b);
            float tt = fminf(fmaxf(dotpa * invd, 0.0f), 1.0f);
            float pa2 = fmaf(py, fmaf(py, 1.0f, -2.0f * ay), pa2_b);
            float d2 = fmaf(tt, fmaf(tt, denom, -2.0f * dotpa), pa2);
            float d = sqrtf(fmaxf(d2, 0.0f));
            float v = fmaxf(d - ws, 0.0f);
            minv[ry] = fminf(minv[ry], v);
        }
    }

    const float* pb = pred + (size_t)b * HWSZ + (size_t)y0 * WW + t;
    float sq = 0.f;
#pragma unroll
    for (int ry = 0; ry < ROWS_PER_BLK; ++ry) {
        float diff = pb[ry * WW] - minv[ry];
        sq = fmaf(diff, diff, sq);
    }

#pragma unroll
    for (int off = 32; off > 0; off >>= 1) sq += __shfl_down(sq, off, 64);
    if ((t & 63) == 0) swsum[t >> 6] = sq;
    __syncthreads();
    if (t == 0) {
        partials[blk] = swsum[0] + swsum[1] + swsum[2] + swsum[3] + swsum[4] + swsum[5];
    }
}

// ---------------------------------------------------------------------------
// Kernel 4: reduce 256 partials -> mean -> d_out[0]
// ---------------------------------------------------------------------------
__global__ __launch_bounds__(256) void finalize_kernel(
    const float* __restrict__ partials, float* __restrict__ out)
{
    __shared__ float sred[4];
    int t = threadIdx.x;
    float s = partials[t];
#pragma unroll
    for (int off = 32; off > 0; off >>= 1) s += __shfl_down(s, off, 64);
    if ((t & 63) == 0) sred[t >> 6] = s;
    __syncthreads();
    if (t == 0) {
        out[0] = (sred[0] + sred[1] + sred[2] + sred[3]) * (1.0f / (float)(BB * HWSZ));
    }
}

extern "C" void kernel_launch(void* const* d_in, const int* in_sizes, int n_in,
                              void* d_out, int out_size, void* d_ws, size_t ws_size,
                              hipStream_t stream)
{
    const float* pred   = (const float*)d_in[0];   // (8,1,384,384)
    const float* nodes  = (const float*)d_in[1];   // (8,96,2)
    const float* widths = (const float*)d_in[2];   // (8,96)
    const float* fltr   = (const float*)d_in[3];   // (2,1,7,7)
    float* out = (float*)d_out;

    float* ws   = (float*)d_ws;
    float4* hbuf = (float4*)ws;                         // B*HW float4 (16B-aligned base)
    float*  g2   = ws + (size_t)4 * BB * HWSZ;          // B*HW*2 interleaved
    float*  gw2  = g2 + (size_t)2 * BB * HWSZ;          // B*HW*2
    float*  segs = gw2 + (size_t)2 * BB * HWSZ;         // B*95*12
    float*  partials = segs + (size_t)BB * NSEG * SEGF; // 256

    conv_h<<<(BB * HWSZ) / 256, 256, 0, stream>>>(pred, fltr, hbuf);
    conv_v<<<(BB * HWSZ) / 256, 256, 0, stream>>>(hbuf, fltr, (float2*)g2, (float2*)gw2);
    snake_kernel<<<BB, 64, 0, stream>>>(nodes, widths, g2, gw2, segs);
    render_kernel<<<BB * NCHUNK, 384, 0, stream>>>(pred, segs, partials);
    finalize_kernel<<<1, 256, 0, stream>>>(partials, out);
}

// Round 5
// 140.249 us; speedup vs baseline: 1.5150x; 1.0942x over previous
//
#include <hip/hip_runtime.h>
#include <math.h>

#define BB   8
#define HH   384
#define WW   384
#define NN   96
#define HWSZ (HH * WW)
#define NSEG (NN - 1)
#define SEGF 12
#define DMAXV 15.0f
#define ROWS_PER_BLK 12
#define NCHUNK (HH / ROWS_PER_BLK)   // 32
#define CROWS 12                     // conv output rows per block
#define CBANDS (HH / CROWS)          // 32

// ---------------------------------------------------------------------------
// Separable 7x7: fy = outer(dg,g), fx = outer(g,dg). Recover 1-D taps exactly:
// g[j] = sum_i |fy[i][j]| (sum|dg|=1), dg[i] = sum_j fy[i][j] (sum g = 1).
// ---------------------------------------------------------------------------
__device__ inline void load_taps(const float* __restrict__ fltr,
                                 float* __restrict__ sg, float* __restrict__ sdg)
{
    int tid = threadIdx.x;
    if (tid < 7) {
        float s = 0.f;
#pragma unroll
        for (int i = 0; i < 7; ++i) s += fabsf(fltr[i * 7 + tid]);
        sg[tid] = s;
    } else if (tid < 14) {
        int r = tid - 7;
        float s = 0.f;
#pragma unroll
        for (int j = 0; j < 7; ++j) s += fltr[r * 7 + j];
        sdg[r] = s;
    }
    __syncthreads();
}

// ---------------------------------------------------------------------------
// Kernel 1: FUSED separable conv. One thread per column, 12 output rows per
// block. Horizontal pass from global (L1-broadcast row reads); vertical pass
// through a 7-row register ring buffer — no intermediate global buffer.
// Also initializes the render-reduction slots (accum, counter).
// ---------------------------------------------------------------------------
__global__ __launch_bounds__(384) void conv_fused(
    const float* __restrict__ pred, const float* __restrict__ fltr,
    float2* __restrict__ g2, float2* __restrict__ gw2,
    float* __restrict__ accum, unsigned int* __restrict__ counter)
{
    __shared__ float sg[7], sdg[7];
    load_taps(fltr, sg, sdg);
    if (blockIdx.x == 0 && threadIdx.x == 0) {
        atomicExch(accum, 0.0f);
        atomicExch(counter, 0u);
    }

    int blk = blockIdx.x;            // 8 * 32 = 256 blocks
    int b = blk / CBANDS;
    int band = blk - b * CBANDS;
    int y0 = band * CROWS;
    int x = threadIdx.x;             // column 0..383
    const float* pb = pred + (size_t)b * HWSZ;
    bool xin = (x >= 3) && (x < WW - 3);

    float hg[7], hd[7], hga[7], hda[7];

#pragma unroll
    for (int q = 0; q < CROWS + 6; ++q) {
        // ---- horizontal pass for absolute row r = y0 + q - 3 ----
        float vg = 0.f, vd = 0.f, vga = 0.f, vda = 0.f;
        int r = y0 + q - 3;
        if (r >= 0 && r < HH) {
            const float* row = pb + r * WW;
            if (xin) {
#pragma unroll
                for (int k = 0; k < 7; ++k) {
                    float v  = row[x + k - 3];
                    float av = fabsf(v);
                    vg  = fmaf(v,  sg[k],  vg);
                    vd  = fmaf(v,  sdg[k], vd);
                    vga = fmaf(av, sg[k],  vga);
                    vda = fmaf(av, sdg[k], vda);
                }
            } else {
#pragma unroll
                for (int k = 0; k < 7; ++k) {
                    int ix = x + k - 3;
                    float v  = (ix >= 0 && ix < WW) ? row[ix] : 0.f;
                    float av = fabsf(v);
                    vg  = fmaf(v,  sg[k],  vg);
                    vd  = fmaf(v,  sdg[k], vd);
                    vga = fmaf(av, sg[k],  vga);
                    vda = fmaf(av, sdg[k], vda);
                }
            }
        }
        hg[q % 7] = vg; hd[q % 7] = vd; hga[q % 7] = vga; hda[q % 7] = vda;

        // ---- vertical pass: emit output row y = y0 + q - 6 ----
        if (q >= 6) {
            int y = y0 + q - 6;
            float o0 = 0.f, o1 = 0.f, o2 = 0.f, o3 = 0.f;
#pragma unroll
            for (int j = 0; j < 7; ++j) {
                int s = (q - 6 + j) % 7;
                o0 = fmaf(hg[s],  sdg[j], o0);   // ch0: vertical dg, horiz g
                o1 = fmaf(hd[s],  sg[j],  o1);   // ch1: vertical g,  horiz dg
                o2 = fmaf(hga[s], sdg[j], o2);
                o3 = fmaf(hda[s], sg[j],  o3);
            }
            size_t gi = (size_t)b * HWSZ + (size_t)y * WW + x;
            g2[gi]  = make_float2(o0 * 10.f, o1 * 10.f);
            gw2[gi] = make_float2(o2 * 10.f, o3 * 10.f);
        }
    }
}

// bilinear sample of a channel-interleaved 2-ch image; ref-identical math
__device__ inline float2 bilin2i(const float2* __restrict__ img, float py, float px)
{
    float y = fminf(fmaxf(py, 0.0f), (float)(HH - 1));
    float x = fminf(fmaxf(px, 0.0f), (float)(WW - 1));
    int y0 = (int)floorf(y);
    int x0 = (int)floorf(x);
    int y1 = min(y0 + 1, HH - 1);
    int x1 = min(x0 + 1, WW - 1);
    float wy = y - (float)y0;
    float wx = x - (float)x0;
    float2 v00 = img[y0 * WW + x0];
    float2 v01 = img[y0 * WW + x1];
    float2 v10 = img[y1 * WW + x0];
    float2 v11 = img[y1 * WW + x1];
    float w00 = (1.f - wy) * (1.f - wx);
    float w01 = (1.f - wy) * wx;
    float w10 = wy * (1.f - wx);
    float w11 = wy * wx;
    return make_float2(v00.x * w00 + v01.x * w01 + v10.x * w10 + v11.x * w11,
                       v00.y * w00 + v01.y * w01 + v10.y * w10 + v11.y * w11);
}

__device__ inline void write_seg(float* __restrict__ r,
                                 float py, float px, float qy, float qx, float wseg)
{
    float aby = qy - py, abx = qx - px;
    float denom = aby * aby + abx * abx + 1e-8f;
    float aab = py * aby + px * abx;
    float aa  = py * py + px * px;
    float reach = DMAXV + wseg;
    r[0]  = py;   r[1]  = px;
    r[2]  = aby;  r[3]  = abx;
    r[4]  = aab;  r[5]  = denom;
    r[6]  = 1.0f / denom;
    r[7]  = aa;   r[8]  = wseg;
    r[9]  = fminf(py, qy) - reach;
    r[10] = fmaxf(py, qy) + reach;
    r[11] = 0.f;
}

// ---------------------------------------------------------------------------
// Kernel 2: snake evolution — ONE WAVE per sample, thread t owns nodes 2t,2t+1.
// d4 computed directly from the 5-point stencil; shuffles hide under gathers.
// ---------------------------------------------------------------------------
__global__ __launch_bounds__(64) void snake_kernel(
    const float* __restrict__ nodes, const float* __restrict__ widths,
    const float* __restrict__ g2, const float* __restrict__ gw2,
    float* __restrict__ segs)
{
    int b = blockIdx.x;
    int t = threadIdx.x;           // 0..63, active t<48

    const float2* gb  = (const float2*)g2  + (size_t)b * HWSZ;
    const float2* gwb = (const float2*)gw2 + (size_t)b * HWSZ;
    const int HALF = NN / 2;       // 48
    bool act = (t < HALF);
    bool t0 = (t == 0), tl = (t == HALF - 1);

    float ay = 0.f, ax = 0.f, by = 0.f, bx = 0.f;
    if (act) {
        float4 n4 = *(const float4*)(nodes + (size_t)(b * NN + 2 * t) * 2);
        ay = n4.x; ax = n4.y; by = n4.z; bx = n4.w;
    }

    // ---- 50 position steps ----
    for (int s = 0; s < 50; ++s) {
        float2 fa = bilin2i(gb, ay, ax);
        float2 fb = bilin2i(gb, by, bx);

        float aLy = __shfl_up(ay, 1, 64),  aLx = __shfl_up(ax, 1, 64);
        float bLy = __shfl_up(by, 1, 64),  bLx = __shfl_up(bx, 1, 64);
        float aRy = __shfl_down(ay, 1, 64), aRx = __shfl_down(ax, 1, 64);
        float bRy = __shfl_down(by, 1, 64), bRx = __shfl_down(bx, 1, 64);
        bLy = t0 ? ay : bLy;  bLx = t0 ? ax : bLx;
        aRy = tl ? by : aRy;  aRx = tl ? bx : aRx;

        float d2m_y = aLy - 2.f * bLy + ay;
        float d2a_y = bLy - 2.f * ay + by;
        float d2b_y = ay  - 2.f * by + aRy;
        float d2p_y = by  - 2.f * aRy + bRy;
        d2m_y = t0 ? d2a_y : d2m_y;
        d2p_y = tl ? d2b_y : d2p_y;
        float d4a_y = d2m_y - 2.f * d2a_y + d2b_y;
        float d4b_y = d2a_y - 2.f * d2b_y + d2p_y;

        float d2m_x = aLx - 2.f * bLx + ax;
        float d2a_x = bLx - 2.f * ax + bx;
        float d2b_x = ax  - 2.f * bx + aRx;
        float d2p_x = bx  - 2.f * aRx + bRx;
        d2m_x = t0 ? d2a_x : d2m_x;
        d2p_x = tl ? d2b_x : d2p_x;
        float d4a_x = d2m_x - 2.f * d2a_x + d2b_x;
        float d4b_x = d2a_x - 2.f * d2b_x + d2p_x;

        ay += 0.1f * (0.01f * d2a_y - 0.01f * d4a_y + fa.x);
        ax += 0.1f * (0.01f * d2a_x - 0.01f * d4a_x + fa.y);
        by += 0.1f * (0.01f * d2b_y - 0.01f * d4b_y + fb.x);
        bx += 0.1f * (0.01f * d2b_x - 0.01f * d4b_x + fb.y);
    }

    // ---- tangent / outward normal ----
    {
        float bLy = __shfl_up(by, 1, 64), bLx = __shfl_up(bx, 1, 64);
        float aRy = __shfl_down(ay, 1, 64), aRx = __shfl_down(ax, 1, 64);
        float tay = 0.5f * (by - bLy), tax = 0.5f * (bx - bLx);
        if (t0) { tay = by - ay; tax = bx - ax; }
        float tby = 0.5f * (aRy - ay), tbx = 0.5f * (aRx - ax);
        if (tl) { tby = by - ay; tbx = bx - ax; }

        float na0 = -tax, na1 = tay;
        float nrm = sqrtf(na0 * na0 + na1 * na1) + 1e-6f;
        float nay = na0 / nrm, nax = na1 / nrm;
        float nb0 = -tbx, nb1 = tby;
        nrm = sqrtf(nb0 * nb0 + nb1 * nb1) + 1e-6f;
        float nby = nb0 / nrm, nbx = nb1 / nrm;

        float wa = 0.f, wb = 0.f;
        if (act) { wa = widths[b * NN + 2 * t]; wb = widths[b * NN + 2 * t + 1]; }
        for (int s = 0; s < 10; ++s) {
            float2 pa = bilin2i(gwb, ay + wa * nay, ax + wa * nax);
            float2 ma = bilin2i(gwb, ay - wa * nay, ax - wa * nax);
            float2 pb = bilin2i(gwb, by + wb * nby, bx + wb * nbx);
            float2 mb = bilin2i(gwb, by - wb * nby, bx - wb * nbx);
            float fa = 0.5f * ((pa.x * nay + pa.y * nax) - (ma.x * nay + ma.y * nax));
            float fb = 0.5f * ((pb.x * nby + pb.y * nbx) - (mb.x * nby + mb.y * nbx));
            wa = fmaxf(wa + 0.1f * fa, 0.5f);
            wb = fmaxf(wb + 0.1f * fb, 0.5f);
        }

        float aRy2 = __shfl_down(ay, 1, 64), aRx2 = __shfl_down(ax, 1, 64);
        float waR  = __shfl_down(wa, 1, 64);
        if (act) {
            float* r0 = segs + (size_t)(b * NSEG + 2 * t) * SEGF;
            write_seg(r0, ay, ax, by, bx, 0.5f * (wa + wb));
            if (t < HALF - 1) {
                float* r1 = segs + (size_t)(b * NSEG + 2 * t + 1) * SEGF;
                write_seg(r1, by, bx, aRy2, aRx2, 0.5f * (wb + waR));
            }
        }
    }
}

// ---------------------------------------------------------------------------
// Kernel 3: render 12 rows per block (256 blocks) + fused grid reduction.
// 256 staggered blocks x 2 device atomics — no storm. Last block writes mean.
// ---------------------------------------------------------------------------
__global__ __launch_bounds__(384) void render_kernel(
    const float* __restrict__ pred, const float* __restrict__ segs,
    float* __restrict__ accum, unsigned int* __restrict__ counter,
    float* __restrict__ out)
{
    __shared__ float ss[NSEG * SEGF];
    __shared__ int slo, shi;
    __shared__ float swsum[6];

    int blk = blockIdx.x;
    int b = blk / NCHUNK;
    int chunk = blk - b * NCHUNK;
    int y0 = chunk * ROWS_PER_BLK;
    int t = threadIdx.x;

    const float* sb = segs + (size_t)b * NSEG * SEGF;
    for (int j = t; j < NSEG * SEGF; j += 384) ss[j] = sb[j];
    if (t == 0) { slo = NSEG; shi = -1; }
    __syncthreads();

    float cy0 = (float)y0, cy1 = (float)(y0 + ROWS_PER_BLK - 1);
    if (t < NSEG) {
        float ylo = ss[t * SEGF + 9];
        float yhi = ss[t * SEGF + 10];
        if (yhi >= cy0 && ylo <= cy1) {
            atomicMin(&slo, t);
            atomicMax(&shi, t);
        }
    }
    __syncthreads();
    int lo = slo, hi = shi;

    float px = (float)t;
    float px2 = px * px;
    float minv[ROWS_PER_BLK];
#pragma unroll
    for (int r = 0; r < ROWS_PER_BLK; ++r) minv[r] = DMAXV;

    for (int si = lo; si <= hi; ++si) {
        const float* r = ss + si * SEGF;
        float ay = r[0], ax = r[1], aby = r[2], abx = r[3];
        float aab = r[4], denom = r[5], invd = r[6], aa = r[7], ws = r[8];
        float dotpa_b = fmaf(px, abx, -aab);
        float pa2_b   = fmaf(px, -2.0f * ax, px2 + aa);
#pragma unroll
        for (int ry = 0; ry < ROWS_PER_BLK; ++ry) {
            float py = (float)(y0 + ry);
            float dotpa = fmaf(py, aby, dotpa_b);
            float tt = fminf(fmaxf(dotpa * invd, 0.0f), 1.0f);
            float pa2 = fmaf(py, fmaf(py, 1.0f, -2.0f * ay), pa2_b);
            float d2 = fmaf(tt, fmaf(tt, denom, -2.0f * dotpa), pa2);
            float d = sqrtf(fmaxf(d2, 0.0f));
            float v = fmaxf(d - ws, 0.0f);
            minv[ry] = fminf(minv[ry], v);
        }
    }

    const float* pb = pred + (size_t)b * HWSZ + (size_t)y0 * WW + t;
    float sq = 0.f;
#pragma unroll
    for (int ry = 0; ry < ROWS_PER_BLK; ++ry) {
        float diff = pb[ry * WW] - minv[ry];
        sq = fmaf(diff, diff, sq);
    }

#pragma unroll
    for (int off = 32; off > 0; off >>= 1) sq += __shfl_down(sq, off, 64);
    if ((t & 63) == 0) swsum[t >> 6] = sq;
    __syncthreads();
    if (t == 0) {
        float tot = swsum[0] + swsum[1] + swsum[2] + swsum[3] + swsum[4] + swsum[5];
        atomicAdd(accum, tot);
        __threadfence();
        unsigned int done = atomicAdd(counter, 1u);
        if (done == (unsigned int)(BB * NCHUNK - 1)) {
            float total = atomicAdd(accum, 0.0f);   // coherent re-read
            out[0] = total * (1.0f / (float)(BB * HWSZ));
        }
    }
}

extern "C" void kernel_launch(void* const* d_in, const int* in_sizes, int n_in,
                              void* d_out, int out_size, void* d_ws, size_t ws_size,
                              hipStream_t stream)
{
    const float* pred   = (const float*)d_in[0];   // (8,1,384,384)
    const float* nodes  = (const float*)d_in[1];   // (8,96,2)
    const float* widths = (const float*)d_in[2];   // (8,96)
    const float* fltr   = (const float*)d_in[3];   // (2,1,7,7)
    float* out = (float*)d_out;

    float* ws   = (float*)d_ws;
    float* g2   = ws;                               // B*HW*2 interleaved
    float* gw2  = g2 + (size_t)2 * BB * HWSZ;       // B*HW*2
    float* segs = gw2 + (size_t)2 * BB * HWSZ;      // B*95*12
    float* accum = segs + (size_t)BB * NSEG * SEGF; // 1
    unsigned int* counter = (unsigned int*)(accum + 1);

    conv_fused<<<BB * CBANDS, 384, 0, stream>>>(pred, fltr, (float2*)g2, (float2*)gw2,
                                                accum, counter);
    snake_kernel<<<BB, 64, 0, stream>>>(nodes, widths, g2, gw2, segs);
    render_kernel<<<BB * NCHUNK, 384, 0, stream>>>(pred, segs, accum, counter, out);
}

// Round 6
// 135.405 us; speedup vs baseline: 1.5692x; 1.0358x over previous
//
#include <hip/hip_runtime.h>
#include <math.h>

#define BB   8
#define HH   384
#define WW   384
#define NN   96
#define HWSZ (HH * WW)
#define NSEG (NN - 1)
#define SEGF 12
#define DMAXV 15.0f
#define ROWS_PER_BLK 12
#define NCHUNK (HH / ROWS_PER_BLK)   // 32
#define CROWS 12                     // conv output rows per block
#define CBANDS (HH / CROWS)          // 32

// ---------------------------------------------------------------------------
// Separable 7x7: fy = outer(dg,g), fx = outer(g,dg). Recover 1-D taps exactly:
// g[j] = sum_i |fy[i][j]| (sum|dg|=1), dg[i] = sum_j fy[i][j] (sum g = 1).
// ---------------------------------------------------------------------------
__device__ inline void load_taps(const float* __restrict__ fltr,
                                 float* __restrict__ sg, float* __restrict__ sdg)
{
    int tid = threadIdx.x;
    if (tid < 7) {
        float s = 0.f;
#pragma unroll
        for (int i = 0; i < 7; ++i) s += fabsf(fltr[i * 7 + tid]);
        sg[tid] = s;
    } else if (tid < 14) {
        int r = tid - 7;
        float s = 0.f;
#pragma unroll
        for (int j = 0; j < 7; ++j) s += fltr[r * 7 + j];
        sdg[r] = s;
    }
    __syncthreads();
}

// ---------------------------------------------------------------------------
// Kernel 1: FUSED separable conv, XCD-co-located: block blk handles image
// b = blk & 7 (round-robin block->XCD mapping puts image b's gradient lines
// in XCD b's L2, which snake block b then gathers from locally).
// Vertical pass through a 7-row register ring buffer; no intermediate buffer.
// ---------------------------------------------------------------------------
__global__ __launch_bounds__(384) void conv_fused(
    const float* __restrict__ pred, const float* __restrict__ fltr,
    float2* __restrict__ g2, float2* __restrict__ gw2,
    float* __restrict__ accum, unsigned int* __restrict__ counter)
{
    __shared__ float sg[7], sdg[7];
    load_taps(fltr, sg, sdg);
    if (blockIdx.x == 0 && threadIdx.x == 0) {
        atomicExch(accum, 0.0f);
        atomicExch(counter, 0u);
    }

    int blk = blockIdx.x;            // 8 * 32 = 256 blocks
    int b = blk & 7;                 // XCD co-location swizzle
    int band = blk >> 3;
    int y0 = band * CROWS;
    int x = threadIdx.x;             // column 0..383
    const float* pb = pred + (size_t)b * HWSZ;
    bool xin = (x >= 3) && (x < WW - 3);

    float hg[7], hd[7], hga[7], hda[7];

#pragma unroll
    for (int q = 0; q < CROWS + 6; ++q) {
        // ---- horizontal pass for absolute row r = y0 + q - 3 ----
        float vg = 0.f, vd = 0.f, vga = 0.f, vda = 0.f;
        int r = y0 + q - 3;
        if (r >= 0 && r < HH) {
            const float* row = pb + r * WW;
            if (xin) {
#pragma unroll
                for (int k = 0; k < 7; ++k) {
                    float v  = row[x + k - 3];
                    float av = fabsf(v);
                    vg  = fmaf(v,  sg[k],  vg);
                    vd  = fmaf(v,  sdg[k], vd);
                    vga = fmaf(av, sg[k],  vga);
                    vda = fmaf(av, sdg[k], vda);
                }
            } else {
#pragma unroll
                for (int k = 0; k < 7; ++k) {
                    int ix = x + k - 3;
                    float v  = (ix >= 0 && ix < WW) ? row[ix] : 0.f;
                    float av = fabsf(v);
                    vg  = fmaf(v,  sg[k],  vg);
                    vd  = fmaf(v,  sdg[k], vd);
                    vga = fmaf(av, sg[k],  vga);
                    vda = fmaf(av, sdg[k], vda);
                }
            }
        }
        hg[q % 7] = vg; hd[q % 7] = vd; hga[q % 7] = vga; hda[q % 7] = vda;

        // ---- vertical pass: emit output row y = y0 + q - 6 ----
        if (q >= 6) {
            int y = y0 + q - 6;
            float o0 = 0.f, o1 = 0.f, o2 = 0.f, o3 = 0.f;
#pragma unroll
            for (int j = 0; j < 7; ++j) {
                int s = (q - 6 + j) % 7;
                o0 = fmaf(hg[s],  sdg[j], o0);   // ch0: vertical dg, horiz g
                o1 = fmaf(hd[s],  sg[j],  o1);   // ch1: vertical g,  horiz dg
                o2 = fmaf(hga[s], sdg[j], o2);
                o3 = fmaf(hda[s], sg[j],  o3);
            }
            size_t gi = (size_t)b * HWSZ + (size_t)y * WW + x;
            g2[gi]  = make_float2(o0 * 10.f, o1 * 10.f);
            gw2[gi] = make_float2(o2 * 10.f, o3 * 10.f);
        }
    }
}

// ---------------------------------------------------------------------------
// Bilinear sample, channel-interleaved 2-ch image; ref-identical math.
// Paired 16-B row loads: corners (x0,x0+1) are contiguous float2s -> one
// dwordx4 per row instead of two dwordx2. Border clamp via select; the 8-B
// overread at row/image end stays inside the workspace (harmless).
// ---------------------------------------------------------------------------
__device__ inline float2 bilin2i(const float2* __restrict__ img, float py, float px)
{
    float y = fminf(fmaxf(py, 0.0f), (float)(HH - 1));
    float x = fminf(fmaxf(px, 0.0f), (float)(WW - 1));
    int y0 = (int)floorf(y);
    int x0 = (int)floorf(x);
    int y1 = min(y0 + 1, HH - 1);
    bool xedge = (x0 + 1 > WW - 1);          // x1 clamped to x0
    float wy = y - (float)y0;
    float wx = x - (float)x0;
    float4 r0 = *(const float4*)(img + y0 * WW + x0);   // v00 | v01
    float4 r1 = *(const float4*)(img + y1 * WW + x0);   // v10 | v11
    float2 v00 = make_float2(r0.x, r0.y);
    float2 v01 = xedge ? v00 : make_float2(r0.z, r0.w);
    float2 v10 = make_float2(r1.x, r1.y);
    float2 v11 = xedge ? v10 : make_float2(r1.z, r1.w);
    float w00 = (1.f - wy) * (1.f - wx);
    float w01 = (1.f - wy) * wx;
    float w10 = wy * (1.f - wx);
    float w11 = wy * wx;
    return make_float2(v00.x * w00 + v01.x * w01 + v10.x * w10 + v11.x * w11,
                       v00.y * w00 + v01.y * w01 + v10.y * w10 + v11.y * w11);
}

__device__ inline void write_seg(float* __restrict__ r,
                                 float py, float px, float qy, float qx, float wseg)
{
    float aby = qy - py, abx = qx - px;
    float denom = aby * aby + abx * abx + 1e-8f;
    float aab = py * aby + px * abx;
    float aa  = py * py + px * px;
    float reach = DMAXV + wseg;
    r[0]  = py;   r[1]  = px;
    r[2]  = aby;  r[3]  = abx;
    r[4]  = aab;  r[5]  = denom;
    r[6]  = 1.0f / denom;
    r[7]  = aa;   r[8]  = wseg;
    r[9]  = fminf(py, qy) - reach;
    r[10] = fmaxf(py, qy) + reach;
    r[11] = 0.f;
}

// ---------------------------------------------------------------------------
// Kernel 2: snake evolution — ONE WAVE per sample, thread t owns nodes 2t,2t+1.
// Block b -> XCD b, where conv just parked image b's gradient lines in L2.
// ---------------------------------------------------------------------------
__global__ __launch_bounds__(64) void snake_kernel(
    const float* __restrict__ nodes, const float* __restrict__ widths,
    const float* __restrict__ g2, const float* __restrict__ gw2,
    float* __restrict__ segs)
{
    int b = blockIdx.x;
    int t = threadIdx.x;           // 0..63, active t<48

    const float2* gb  = (const float2*)g2  + (size_t)b * HWSZ;
    const float2* gwb = (const float2*)gw2 + (size_t)b * HWSZ;
    const int HALF = NN / 2;       // 48
    bool act = (t < HALF);
    bool t0 = (t == 0), tl = (t == HALF - 1);

    float ay = 0.f, ax = 0.f, by = 0.f, bx = 0.f;
    if (act) {
        float4 n4 = *(const float4*)(nodes + (size_t)(b * NN + 2 * t) * 2);
        ay = n4.x; ax = n4.y; by = n4.z; bx = n4.w;
    }

    // ---- 50 position steps ----
    for (int s = 0; s < 50; ++s) {
        float2 fa = bilin2i(gb, ay, ax);
        float2 fb = bilin2i(gb, by, bx);

        float aLy = __shfl_up(ay, 1, 64),  aLx = __shfl_up(ax, 1, 64);
        float bLy = __shfl_up(by, 1, 64),  bLx = __shfl_up(bx, 1, 64);
        float aRy = __shfl_down(ay, 1, 64), aRx = __shfl_down(ax, 1, 64);
        float bRy = __shfl_down(by, 1, 64), bRx = __shfl_down(bx, 1, 64);
        bLy = t0 ? ay : bLy;  bLx = t0 ? ax : bLx;
        aRy = tl ? by : aRy;  aRx = tl ? bx : aRx;

        float d2m_y = aLy - 2.f * bLy + ay;
        float d2a_y = bLy - 2.f * ay + by;
        float d2b_y = ay  - 2.f * by + aRy;
        float d2p_y = by  - 2.f * aRy + bRy;
        d2m_y = t0 ? d2a_y : d2m_y;
        d2p_y = tl ? d2b_y : d2p_y;
        float d4a_y = d2m_y - 2.f * d2a_y + d2b_y;
        float d4b_y = d2a_y - 2.f * d2b_y + d2p_y;

        float d2m_x = aLx - 2.f * bLx + ax;
        float d2a_x = bLx - 2.f * ax + bx;
        float d2b_x = ax  - 2.f * bx + aRx;
        float d2p_x = bx  - 2.f * aRx + bRx;
        d2m_x = t0 ? d2a_x : d2m_x;
        d2p_x = tl ? d2b_x : d2p_x;
        float d4a_x = d2m_x - 2.f * d2a_x + d2b_x;
        float d4b_x = d2a_x - 2.f * d2b_x + d2p_x;

        ay += 0.1f * (0.01f * d2a_y - 0.01f * d4a_y + fa.x);
        ax += 0.1f * (0.01f * d2a_x - 0.01f * d4a_x + fa.y);
        by += 0.1f * (0.01f * d2b_y - 0.01f * d4b_y + fb.x);
        bx += 0.1f * (0.01f * d2b_x - 0.01f * d4b_x + fb.y);
    }

    // ---- tangent / outward normal ----
    {
        float bLy = __shfl_up(by, 1, 64), bLx = __shfl_up(bx, 1, 64);
        float aRy = __shfl_down(ay, 1, 64), aRx = __shfl_down(ax, 1, 64);
        float tay = 0.5f * (by - bLy), tax = 0.5f * (bx - bLx);
        if (t0) { tay = by - ay; tax = bx - ax; }
        float tby = 0.5f * (aRy - ay), tbx = 0.5f * (aRx - ax);
        if (tl) { tby = by - ay; tbx = bx - ax; }

        float na0 = -tax, na1 = tay;
        float nrm = sqrtf(na0 * na0 + na1 * na1) + 1e-6f;
        float nay = na0 / nrm, nax = na1 / nrm;
        float nb0 = -tbx, nb1 = tby;
        nrm = sqrtf(nb0 * nb0 + nb1 * nb1) + 1e-6f;
        float nby = nb0 / nrm, nbx = nb1 / nrm;

        float wa = 0.f, wb = 0.f;
        if (act) { wa = widths[b * NN + 2 * t]; wb = widths[b * NN + 2 * t + 1]; }
        for (int s = 0; s < 10; ++s) {
            float2 pa = bilin2i(gwb, ay + wa * nay, ax + wa * nax);
            float2 ma = bilin2i(gwb, ay - wa * nay, ax - wa * nax);
            float2 pb = bilin2i(gwb, by + wb * nby, bx + wb * nbx);
            float2 mb = bilin2i(gwb, by - wb * nby, bx - wb * nbx);
            float fa = 0.5f * ((pa.x * nay + pa.y * nax) - (ma.x * nay + ma.y * nax));
            float fb = 0.5f * ((pb.x * nby + pb.y * nbx) - (mb.x * nby + mb.y * nbx));
            wa = fmaxf(wa + 0.1f * fa, 0.5f);
            wb = fmaxf(wb + 0.1f * fb, 0.5f);
        }

        float aRy2 = __shfl_down(ay, 1, 64), aRx2 = __shfl_down(ax, 1, 64);
        float waR  = __shfl_down(wa, 1, 64);
        if (act) {
            float* r0 = segs + (size_t)(b * NSEG + 2 * t) * SEGF;
            write_seg(r0, ay, ax, by, bx, 0.5f * (wa + wb));
            if (t < HALF - 1) {
                float* r1 = segs + (size_t)(b * NSEG + 2 * t + 1) * SEGF;
                write_seg(r1, by, bx, aRy2, aRx2, 0.5f * (wb + waR));
            }
        }
    }
}

// ---------------------------------------------------------------------------
// Kernel 3: render 12 rows per block (256 blocks) + fused grid reduction.
// XCD swizzle: image b handled by blocks with blk&7==b (segs L2 locality).
// ---------------------------------------------------------------------------
__global__ __launch_bounds__(384) void render_kernel(
    const float* __restrict__ pred, const float* __restrict__ segs,
    float* __restrict__ accum, unsigned int* __restrict__ counter,
    float* __restrict__ out)
{
    __shared__ float ss[NSEG * SEGF];
    __shared__ int slo, shi;
    __shared__ float swsum[6];

    int blk = blockIdx.x;
    int b = blk & 7;                 // XCD co-location swizzle
    int chunk = blk >> 3;
    int y0 = chunk * ROWS_PER_BLK;
    int t = threadIdx.x;

    const float* sb = segs + (size_t)b * NSEG * SEGF;
    for (int j = t; j < NSEG * SEGF; j += 384) ss[j] = sb[j];
    if (t == 0) { slo = NSEG; shi = -1; }
    __syncthreads();

    float cy0 = (float)y0, cy1 = (float)(y0 + ROWS_PER_BLK - 1);
    if (t < NSEG) {
        float ylo = ss[t * SEGF + 9];
        float yhi = ss[t * SEGF + 10];
        if (yhi >= cy0 && ylo <= cy1) {
            atomicMin(&slo, t);
            atomicMax(&shi, t);
        }
    }
    __syncthreads();
    int lo = slo, hi = shi;

    float px = (float)t;
    float px2 = px * px;
    float minv[ROWS_PER_BLK];
#pragma unroll
    for (int r = 0; r < ROWS_PER_BLK; ++r) minv[r] = DMAXV;

    for (int si = lo; si <= hi; ++si) {
        const float* r = ss + si * SEGF;
        float ay = r[0], ax = r[1], aby = r[2], abx = r[3];
        float aab = r[4], denom = r[5], invd = r[6], aa = r[7], ws = r[8];
        float dotpa_b = fmaf(px, abx, -aab);
        float pa2_b   = fmaf(px, -2.0f * ax, px2 + aa);
#pragma unroll
        for (int ry = 0; ry < ROWS_PER_BLK; ++ry) {
            float py = (float)(y0 + ry);
            float dotpa = fmaf(py, aby, dotpa_b);
            float tt = fminf(fmaxf(dotpa * invd, 0.0f), 1.0f);
            float pa2 = fmaf(py, fmaf(py, 1.0f, -2.0f * ay), pa2_b);
            float d2 = fmaf(tt, fmaf(tt, denom, -2.0f * dotpa), pa2);
            float d = sqrtf(fmaxf(d2, 0.0f));
            float v = fmaxf(d - ws, 0.0f);
            minv[ry] = fminf(minv[ry], v);
        }
    }

    const float* pb = pred + (size_t)b * HWSZ + (size_t)y0 * WW + t;
    float sq = 0.f;
#pragma unroll
    for (int ry = 0; ry < ROWS_PER_BLK; ++ry) {
        float diff = pb[ry * WW] - minv[ry];
        sq = fmaf(diff, diff, sq);
    }

#pragma unroll
    for (int off = 32; off > 0; off >>= 1) sq += __shfl_down(sq, off, 64);
    if ((t & 63) == 0) swsum[t >> 6] = sq;
    __syncthreads();
    if (t == 0) {
        float tot = swsum[0] + swsum[1] + swsum[2] + swsum[3] + swsum[4] + swsum[5];
        atomicAdd(accum, tot);
        __threadfence();
        unsigned int done = atomicAdd(counter, 1u);
        if (done == (unsigned int)(BB * NCHUNK - 1)) {
            float total = atomicAdd(accum, 0.0f);   // coherent re-read
            out[0] = total * (1.0f / (float)(BB * HWSZ));
        }
    }
}

extern "C" void kernel_launch(void* const* d_in, const int* in_sizes, int n_in,
                              void* d_out, int out_size, void* d_ws, size_t ws_size,
                              hipStream_t stream)
{
    const float* pred   = (const float*)d_in[0];   // (8,1,384,384)
    const float* nodes  = (const float*)d_in[1];   // (8,96,2)
    const float* widths = (const float*)d_in[2];   // (8,96)
    const float* fltr   = (const float*)d_in[3];   // (2,1,7,7)
    float* out = (float*)d_out;

    float* ws   = (float*)d_ws;
    float* g2   = ws;                               // B*HW*2 interleaved
    float* gw2  = g2 + (size_t)2 * BB * HWSZ;       // B*HW*2
    float* segs = gw2 + (size_t)2 * BB * HWSZ;      // B*95*12
    float* accum = segs + (size_t)BB * NSEG * SEGF; // 1
    unsigned int* counter = (unsigned int*)(accum + 1);

    conv_fused<<<BB * CBANDS, 384, 0, stream>>>(pred, fltr, (float2*)g2, (float2*)gw2,
                                                accum, counter);
    snake_kernel<<<BB, 64, 0, stream>>>(nodes, widths, g2, gw2, segs);
    render_kernel<<<BB * NCHUNK, 384, 0, stream>>>(pred, segs, accum, counter, out);
}